// Round 6
// baseline (127.146 us; speedup 1.0000x reference)
//
#include <hip/hip_runtime.h>
#include <hip/hip_bf16.h>

// InfoNCE loss, N=4096, D=256, tau=0.5.
// loss = (1/2n)[ sum_r log(sum_{k!=r} exp(2*Z_r.Z_k)) - 2*sum_i 2*(xn_i.yn_i) ]
// Z = concat(xn, yn) row-normalized; scores in [-2,2] -> no running max needed.
// 2/tau*log2(e) folded into A-side bf16 fragments; epilogue = exp2 + add.
// R6: R=2 B-reuse kept (each LDS B-read feeds 2 MFMAs). Occupancy restored to
// 16 waves/CU as FOUR independent 4-wave blocks (R5 lesson: one 8-wave
// lockstepped block at 66048B LDS -> 1 block/CU, MfmaUtil 12%). LDS is exactly
// 32768 B/block (2 x 16 KB tiles); finalize scratch reuses smem (no extra LDS).

#define NROWS 8192
#define DDIM  256
#define BM    128        // rows per block = 4 waves * 32 rows
#define BN    32         // cols per LDS tile (16 KB)
#define COLSPLIT 16      // grid = 64 * 16 = 1024 blocks = 4/CU exactly
#define COLS_PER (NROWS / COLSPLIT)   // 512
#define NT (COLS_PER / BN)            // 16 tiles
#define NBLOCKS 1024

typedef __attribute__((ext_vector_type(8))) __bf16 bf16x8_t;
typedef __attribute__((ext_vector_type(4))) float  f32x4_t;

typedef __attribute__((address_space(1))) const void* as1_cvp;
typedef __attribute__((address_space(3))) void*       as3_vp;

#if __has_builtin(__builtin_amdgcn_exp2f)
#define EXP2F __builtin_amdgcn_exp2f
#else
#define EXP2F exp2f
#endif

#define TWO_LOG2E 2.8853900817779268f

// ---- K1: normalize rows + per-pair diag dot + zero rowsum/counter ----
__global__ __launch_bounds__(256) void normalize_diag_kernel(
    const float* __restrict__ x, const float* __restrict__ y,
    __hip_bfloat16* __restrict__ zb, float* __restrict__ rowdiag,
    float* __restrict__ rowsum, int* __restrict__ counter) {
  const int g = blockIdx.x * 256 + threadIdx.x;
  if (g < NROWS) rowsum[g] = 0.f;
  if (g == 0) *counter = 0;

  const int w = threadIdx.x >> 6, lane = threadIdx.x & 63;
  const int i = blockIdx.x * 4 + w;           // 0..4095
  const float4 xv = ((const float4*)(x + (size_t)i * DDIM))[lane];
  const float4 yv = ((const float4*)(y + (size_t)i * DDIM))[lane];
  float ssx = xv.x * xv.x + xv.y * xv.y + xv.z * xv.z + xv.w * xv.w;
  float ssy = yv.x * yv.x + yv.y * yv.y + yv.z * yv.z + yv.w * yv.w;
  float sxy = xv.x * yv.x + xv.y * yv.y + xv.z * yv.z + xv.w * yv.w;
  #pragma unroll
  for (int off = 32; off > 0; off >>= 1) {
    ssx += __shfl_xor(ssx, off, 64);
    ssy += __shfl_xor(ssy, off, 64);
    sxy += __shfl_xor(sxy, off, 64);
  }
  const float sclx = 1.0f / fmaxf(sqrtf(ssx), 1e-8f);
  const float scly = 1.0f / fmaxf(sqrtf(ssy), 1e-8f);
  __hip_bfloat16 px[4], py[4];
  px[0] = __float2bfloat16(xv.x * sclx); px[1] = __float2bfloat16(xv.y * sclx);
  px[2] = __float2bfloat16(xv.z * sclx); px[3] = __float2bfloat16(xv.w * sclx);
  py[0] = __float2bfloat16(yv.x * scly); py[1] = __float2bfloat16(yv.y * scly);
  py[2] = __float2bfloat16(yv.z * scly); py[3] = __float2bfloat16(yv.w * scly);
  *(short4*)(zb + (size_t)i * DDIM + lane * 4)            = *(short4*)px;
  *(short4*)(zb + (size_t)(i + 4096) * DDIM + lane * 4)   = *(short4*)py;
  if (lane == 0) rowdiag[i] = 2.0f * sxy * sclx * scly;   // target score (f32)
}

// ---- K2: fused Gram + per-row sum of exp + last-block finalize ----
// 256 threads = 4 waves; each wave owns 32 rows (2 A-sets). BN=32 keys
// double-buffered in LDS (2 x 16 KB = 32768 B exactly -> 4 blocks/CU),
// prefetched via global_load_lds with XOR-swizzled global source addresses
// (linear LDS dest); one vmcnt(0)+barrier per tile.
__global__ __launch_bounds__(256) void gram_lse_kernel(
    const __hip_bfloat16* __restrict__ zbh, float* __restrict__ rowsum,
    const float* __restrict__ rowdiag, int* __restrict__ counter,
    float* __restrict__ out) {
  __shared__ short smem[2][BN * DDIM];  // exactly 32 KB, no other LDS

  const short* zs = (const short*)zbh;
  const char* zbytes = (const char*)zs;
  const int tid  = threadIdx.x;
  const int w    = tid >> 6;    // 0..3
  const int lane = tid & 63;
  const int lhi  = lane >> 4;   // 0..3
  const int llo  = lane & 15;   // 0..15
  const int i0 = (blockIdx.x >> 4) * BM;            // row-tile base (64 tiles)
  const int c0 = (blockIdx.x & 15) * COLS_PER;      // column-range base
  // rows [i0,i0+128) meet cols [c0,c0+512) on the diagonal iff:
  const bool has_diag = ((blockIdx.x >> 6) == (blockIdx.x & 15));

  // Two A-fragment sets: rows arow0 and arow0+16, full K=256, pre-scaled by
  // bf16(2*log2e) so MFMA yields score*log2(e) directly.
  const int arow0 = i0 + w * 32 + llo;
  const float TBF = __bfloat162float(__float2bfloat16(TWO_LOG2E));
  bf16x8_t afa[8], afb[8];
  #pragma unroll
  for (int ks = 0; ks < 8; ++ks) {
    afa[ks] = *(const bf16x8_t*)(zs + (size_t)arow0 * DDIM + ks * 32 + lhi * 8);
    afb[ks] = *(const bf16x8_t*)(zs + (size_t)(arow0 + 16) * DDIM + ks * 32 + lhi * 8);
    #pragma unroll
    for (int e = 0; e < 8; ++e) {
      afa[ks][e] = (__bf16)((float)afa[ks][e] * TBF);
      afb[ks][e] = (__bf16)((float)afb[ks][e] * TBF);
    }
  }

  // Staging offsets: 256 threads x 16 B x 4 its = 16 KB tile. Linear LDS dest
  // (wave-uniform base + lane*16), XOR-swizzle applied on the global source:
  //   lds[cr*512 + slot*16 .. +16) = row (cb+cr) bytes [(slot ^ (cr&31))*16 ..)
  int soff[4], loff[4];
  #pragma unroll
  for (int it = 0; it < 4; ++it) {
    const int o    = it * 4096 + tid * 16;
    const int cr   = o >> 9;            // 0..31
    const int slot = (o >> 4) & 31;
    soff[it] = cr * 512 + ((slot ^ cr) << 4);
    loff[it] = it * 4096 + w * 1024;    // wave-uniform dest base
  }

#define STAGE(buf, ct_) do {                                                  \
    const size_t cbase = (size_t)(c0 + (ct_) * BN) * 512;                     \
    _Pragma("unroll")                                                         \
    for (int it = 0; it < 4; ++it) {                                          \
      __builtin_amdgcn_global_load_lds(                                       \
          (as1_cvp)(zbytes + cbase + (size_t)soff[it]),                       \
          (as3_vp)((char*)smem[buf] + loff[it]), 16, 0, 0);                   \
    }                                                                         \
  } while (0)

  float racc0[4] = {0.f, 0.f, 0.f, 0.f};
  float racc1[4] = {0.f, 0.f, 0.f, 0.f};
  const int gr0 = i0 + w * 32 + lhi * 4;   // C/D row = (lane>>4)*4 + j
  const int gr1 = gr0 + 16;

  STAGE(0, 0);
  asm volatile("s_waitcnt vmcnt(0)" ::: "memory");
  __syncthreads();
  int cur = 0;

  for (int ct = 0; ct < NT; ++ct) {
    if (ct + 1 < NT) STAGE(cur ^ 1, ct + 1);   // prefetch overlaps compute
    const int cb = c0 + ct * BN;

    #pragma unroll
    for (int nt = 0; nt < 2; ++nt) {
      const int cr = nt * 16 + llo;      // key (column) this lane feeds as B
      f32x4_t acc0 = {0.f, 0.f, 0.f, 0.f};
      f32x4_t acc1 = {0.f, 0.f, 0.f, 0.f};
      #pragma unroll
      for (int ks = 0; ks < 8; ++ks) {
        const int kg = ks * 4 + lhi;     // 16B k-slot
        const bf16x8_t bfrag = *(const bf16x8_t*)(
            (const char*)smem[cur] + cr * 512 + ((kg ^ cr) << 4));
        acc0 = __builtin_amdgcn_mfma_f32_16x16x32_bf16(afa[ks], bfrag, acc0, 0, 0, 0);
        acc1 = __builtin_amdgcn_mfma_f32_16x16x32_bf16(afb[ks], bfrag, acc1, 0, 0, 0);
      }
      if (has_diag) {                    // block-uniform branch (64/1024 blocks)
        const int gc = cb + cr;
        #pragma unroll
        for (int j = 0; j < 4; ++j) {
          racc0[j] += ((gr0 + j) != gc) ? EXP2F(acc0[j]) : 0.f;
          racc1[j] += ((gr1 + j) != gc) ? EXP2F(acc1[j]) : 0.f;
        }
      } else {
        #pragma unroll
        for (int j = 0; j < 4; ++j) {
          racc0[j] += EXP2F(acc0[j]);
          racc1[j] += EXP2F(acc1[j]);
        }
      }
    }
    asm volatile("s_waitcnt vmcnt(0)" ::: "memory");  // prefetched tile landed
    __syncthreads();
    cur ^= 1;
  }
#undef STAGE

  // Per-row partial sums -> global rowsum (16 adds per row address total).
  #pragma unroll
  for (int j = 0; j < 4; ++j) {
    float v0 = racc0[j], v1 = racc1[j];
    v0 += __shfl_xor(v0, 1, 16); v1 += __shfl_xor(v1, 1, 16);
    v0 += __shfl_xor(v0, 2, 16); v1 += __shfl_xor(v1, 2, 16);
    v0 += __shfl_xor(v0, 4, 16); v1 += __shfl_xor(v1, 4, 16);
    v0 += __shfl_xor(v0, 8, 16); v1 += __shfl_xor(v1, 8, 16);
    if (llo == 0) {
      atomicAdd(&rowsum[gr0 + j], v0);
      atomicAdd(&rowsum[gr1 + j], v1);
    }
  }

  // ---- fused finalize: last block to finish reduces the loss ----
  // Scratch lives in reused smem: LDS stays exactly 32768 B (R5 lesson).
  int* flagp   = (int*)&smem[0][0];
  float* wsump = (float*)&smem[0][32];
  __threadfence();
  __syncthreads();                       // smem reads of main loop done
  if (tid == 0) *flagp = (atomicAdd(counter, 1) == NBLOCKS - 1) ? 1 : 0;
  __syncthreads();
  if (!*flagp) return;

  float s = 0.f;
  for (int r = tid; r < NROWS; r += 256) {
    const float v = atomicAdd(&rowsum[r], 0.0f);   // coherent read of others' sums
    s += __logf(v);
  }
  for (int i = tid; i < 4096; i += 256) s -= 2.0f * rowdiag[i];
  #pragma unroll
  for (int off = 32; off > 0; off >>= 1) s += __shfl_xor(s, off, 64);
  if (lane == 0) wsump[w] = s;
  __syncthreads();
  if (tid == 0) out[0] = (wsump[0] + wsump[1] + wsump[2] + wsump[3]) / (float)NROWS;
}

extern "C" void kernel_launch(void* const* d_in, const int* in_sizes, int n_in,
                              void* d_out, int out_size, void* d_ws, size_t ws_size,
                              hipStream_t stream) {
  const float* x = (const float*)d_in[0];
  const float* y = (const float*)d_in[1];
  float* out = (float*)d_out;

  char* ws = (char*)d_ws;
  __hip_bfloat16* zb = (__hip_bfloat16*)ws;                       // 4 MB
  float* rowsum  = (float*)(ws + (size_t)NROWS * DDIM * 2);       // 32 KB
  float* rowdiag = rowsum + NROWS;                                // 16 KB
  int*   counter = (int*)(rowdiag + 4096);                        // 4 B

  normalize_diag_kernel<<<1024, 256, 0, stream>>>(x, y, zb, rowdiag, rowsum, counter);
  gram_lse_kernel<<<NBLOCKS, 256, 0, stream>>>(zb, rowsum, rowdiag, counter, out);
}

// Round 8
// 56.608 us; speedup vs baseline: 2.2461x; 2.2461x over previous
//
#include <hip/hip_runtime.h>
#include <hip/hip_bf16.h>

// InfoNCE loss, N=4096, D=256, tau=0.5.
// loss = (1/2n)[ sum_r log(sum_{k!=r} exp(2*Z_r.Z_k)) - 2*sum_i 2*(xn_i.yn_i) ]
// Z = concat(xn, yn) row-normalized; scores in [-2,2] -> no running max needed.
// 2/tau*log2(e) folded into A-side bf16 fragments; epilogue = exp2 + add.
//
// R7 = R3's proven 43us shell (8-wave/512-thr blocks, BN=64, LDS exactly
// 65536 -> 2 blocks/CU, separate finalize, no counter/threadfence) with ONE
// change: BM=256 (each wave owns 32 rows, two A-frag sets) so every LDS
// B-fragment read feeds 2 MFMAs. R3 was measured AT the ds_read_b128 issue
// wall (8192 b128/CU x 12cyc = 41us ~ 43.2us); this halves it.

#define NROWS 8192
#define DDIM  256
#define BM    256        // rows per block = 8 waves * 32 rows
#define BN    64         // cols per LDS tile (32 KB)
#define COLSPLIT 16      // grid = 32 * 16 = 512 blocks = 2/CU exactly
#define COLS_PER (NROWS / COLSPLIT)   // 512
#define NT (COLS_PER / BN)            // 8 tiles

typedef __attribute__((ext_vector_type(8))) __bf16 bf16x8_t;
typedef __attribute__((ext_vector_type(4))) float  f32x4_t;

typedef __attribute__((address_space(1))) const void* as1_cvp;
typedef __attribute__((address_space(3))) void*       as3_vp;

#if __has_builtin(__builtin_amdgcn_exp2f)
#define EXP2F __builtin_amdgcn_exp2f
#else
#define EXP2F exp2f
#endif

#define TWO_LOG2E 2.8853900817779268f

// ---- K1: normalize rows + per-pair diag dot + zero rowsum ----
__global__ __launch_bounds__(256) void normalize_diag_kernel(
    const float* __restrict__ x, const float* __restrict__ y,
    __hip_bfloat16* __restrict__ zb, float* __restrict__ rowdiag,
    float* __restrict__ rowsum) {
  const int g = blockIdx.x * 256 + threadIdx.x;
  if (g < NROWS) rowsum[g] = 0.f;

  const int w = threadIdx.x >> 6, lane = threadIdx.x & 63;
  const int i = blockIdx.x * 4 + w;           // 0..4095
  const float4 xv = ((const float4*)(x + (size_t)i * DDIM))[lane];
  const float4 yv = ((const float4*)(y + (size_t)i * DDIM))[lane];
  float ssx = xv.x * xv.x + xv.y * xv.y + xv.z * xv.z + xv.w * xv.w;
  float ssy = yv.x * yv.x + yv.y * yv.y + yv.z * yv.z + yv.w * yv.w;
  float sxy = xv.x * yv.x + xv.y * yv.y + xv.z * yv.z + xv.w * yv.w;
  #pragma unroll
  for (int off = 32; off > 0; off >>= 1) {
    ssx += __shfl_xor(ssx, off, 64);
    ssy += __shfl_xor(ssy, off, 64);
    sxy += __shfl_xor(sxy, off, 64);
  }
  const float sclx = 1.0f / fmaxf(sqrtf(ssx), 1e-8f);
  const float scly = 1.0f / fmaxf(sqrtf(ssy), 1e-8f);
  __hip_bfloat16 px[4], py[4];
  px[0] = __float2bfloat16(xv.x * sclx); px[1] = __float2bfloat16(xv.y * sclx);
  px[2] = __float2bfloat16(xv.z * sclx); px[3] = __float2bfloat16(xv.w * sclx);
  py[0] = __float2bfloat16(yv.x * scly); py[1] = __float2bfloat16(yv.y * scly);
  py[2] = __float2bfloat16(yv.z * scly); py[3] = __float2bfloat16(yv.w * scly);
  *(short4*)(zb + (size_t)i * DDIM + lane * 4)            = *(short4*)px;
  *(short4*)(zb + (size_t)(i + 4096) * DDIM + lane * 4)   = *(short4*)py;
  if (lane == 0) rowdiag[i] = 2.0f * sxy * sclx * scly;   // target score (f32)
}

// ---- K2: fused Gram + per-row sum of exp ----
// 512 threads = 8 waves; each wave owns 32 rows (2 A-sets, pre-scaled by
// bf16(2*log2e)). BN=64 keys double-buffered in LDS (2 x 32 KB = 65536 B
// exactly -> 2 blocks/CU), prefetched via global_load_lds with XOR-swizzled
// global source addresses (linear LDS dest); one vmcnt(0)+barrier per tile.
// Each B-frag ds_read_b128 feeds 2 MFMAs -> halves R3's measured LDS wall.
__global__ __launch_bounds__(512) void gram_lse_kernel(
    const __hip_bfloat16* __restrict__ zbh, float* __restrict__ rowsum) {
  __shared__ short smem[2][BN * DDIM];  // exactly 64 KB, no other LDS

  const short* zs = (const short*)zbh;
  const char* zbytes = (const char*)zs;
  const int tid  = threadIdx.x;
  const int w    = tid >> 6;    // 0..7
  const int lane = tid & 63;
  const int lhi  = lane >> 4;   // 0..3
  const int llo  = lane & 15;   // 0..15
  const int i0 = (blockIdx.x >> 4) * BM;            // row-tile base (32 tiles)
  const int c0 = (blockIdx.x & 15) * COLS_PER;      // column-range base
  // rows [i0,i0+256) meet cols [c0,c0+512) on the diagonal iff:
  const bool has_diag = ((blockIdx.x >> 5) == (blockIdx.x & 15));

  // Two A-fragment sets: rows arow0 and arow0+16, full K=256, pre-scaled by
  // bf16(2*log2e) so MFMA yields score*log2(e) directly.
  const int arow0 = i0 + w * 32 + llo;
  const float TBF = __bfloat162float(__float2bfloat16(TWO_LOG2E));
  bf16x8_t afa[8], afb[8];
  #pragma unroll
  for (int ks = 0; ks < 8; ++ks) {
    afa[ks] = *(const bf16x8_t*)(zs + (size_t)arow0 * DDIM + ks * 32 + lhi * 8);
    afb[ks] = *(const bf16x8_t*)(zs + (size_t)(arow0 + 16) * DDIM + ks * 32 + lhi * 8);
    #pragma unroll
    for (int e = 0; e < 8; ++e) {
      afa[ks][e] = (__bf16)((float)afa[ks][e] * TBF);
      afb[ks][e] = (__bf16)((float)afb[ks][e] * TBF);
    }
  }

  // Staging offsets: 512 threads x 16 B x 4 its = 32 KB tile. Linear LDS dest
  // (wave-uniform base + lane*16), XOR-swizzle applied on the global source:
  //   lds[cr*512 + slot*16 .. +16) = row (cb+cr) bytes [(slot ^ (cr&31))*16 ..)
  int soff[4], loff[4];
  #pragma unroll
  for (int it = 0; it < 4; ++it) {
    const int o    = it * 8192 + tid * 16;
    const int cr   = o >> 9;            // 0..63
    const int slot = (o >> 4) & 31;
    soff[it] = cr * 512 + ((slot ^ (cr & 31)) << 4);
    loff[it] = it * 8192 + w * 1024;    // wave-uniform dest base
  }

#define STAGE(buf, ct_) do {                                                  \
    const size_t cbase = (size_t)(c0 + (ct_) * BN) * 512;                     \
    _Pragma("unroll")                                                         \
    for (int it = 0; it < 4; ++it) {                                          \
      __builtin_amdgcn_global_load_lds(                                       \
          (as1_cvp)(zbytes + cbase + (size_t)soff[it]),                       \
          (as3_vp)((char*)smem[buf] + loff[it]), 16, 0, 0);                   \
    }                                                                         \
  } while (0)

  float racc0[4] = {0.f, 0.f, 0.f, 0.f};
  float racc1[4] = {0.f, 0.f, 0.f, 0.f};
  const int gr0 = i0 + w * 32 + lhi * 4;   // C/D row = (lane>>4)*4 + j
  const int gr1 = gr0 + 16;

  STAGE(0, 0);
  asm volatile("s_waitcnt vmcnt(0)" ::: "memory");
  __syncthreads();
  int cur = 0;

  for (int ct = 0; ct < NT; ++ct) {
    if (ct + 1 < NT) STAGE(cur ^ 1, ct + 1);   // prefetch overlaps compute
    const int cb = c0 + ct * BN;

    #pragma unroll
    for (int nt = 0; nt < 4; ++nt) {
      const int cr = nt * 16 + llo;      // key (column) this lane feeds as B
      f32x4_t acc0 = {0.f, 0.f, 0.f, 0.f};
      f32x4_t acc1 = {0.f, 0.f, 0.f, 0.f};
      #pragma unroll
      for (int ks = 0; ks < 8; ++ks) {
        const int kg = ks * 4 + lhi;     // 16B k-slot
        const bf16x8_t bfrag = *(const bf16x8_t*)(
            (const char*)smem[cur] + cr * 512 + ((kg ^ (cr & 31)) << 4));
        acc0 = __builtin_amdgcn_mfma_f32_16x16x32_bf16(afa[ks], bfrag, acc0, 0, 0, 0);
        acc1 = __builtin_amdgcn_mfma_f32_16x16x32_bf16(afb[ks], bfrag, acc1, 0, 0, 0);
      }
      if (has_diag) {                    // block-uniform branch (32/512 blocks)
        const int gc = cb + cr;
        #pragma unroll
        for (int j = 0; j < 4; ++j) {
          racc0[j] += ((gr0 + j) != gc) ? EXP2F(acc0[j]) : 0.f;
          racc1[j] += ((gr1 + j) != gc) ? EXP2F(acc1[j]) : 0.f;
        }
      } else {
        #pragma unroll
        for (int j = 0; j < 4; ++j) {
          racc0[j] += EXP2F(acc0[j]);
          racc1[j] += EXP2F(acc1[j]);
        }
      }
    }
    asm volatile("s_waitcnt vmcnt(0)" ::: "memory");  // prefetched tile landed
    __syncthreads();
    cur ^= 1;
  }
#undef STAGE

  // Per-row partial sums -> global rowsum (16 adds per row address total).
  #pragma unroll
  for (int j = 0; j < 4; ++j) {
    float v0 = racc0[j], v1 = racc1[j];
    v0 += __shfl_xor(v0, 1, 16); v1 += __shfl_xor(v1, 1, 16);
    v0 += __shfl_xor(v0, 2, 16); v1 += __shfl_xor(v1, 2, 16);
    v0 += __shfl_xor(v0, 4, 16); v1 += __shfl_xor(v1, 4, 16);
    v0 += __shfl_xor(v0, 8, 16); v1 += __shfl_xor(v1, 8, 16);
    if (llo == 0) {
      atomicAdd(&rowsum[gr0 + j], v0);
      atomicAdd(&rowsum[gr1 + j], v1);
    }
  }
}

// ------- K3: loss = (sum_r log(rowsum_r) - 2*sum_i rowdiag_i) / 2n -------
__global__ __launch_bounds__(256) void finalize_kernel(
    const float* __restrict__ rowsum, const float* __restrict__ rowdiag,
    float* __restrict__ out) {
  const int t = threadIdx.x;
  float s = 0.f;
  for (int r4 = t; r4 < NROWS / 4; r4 += 256) {
    const float4 v = ((const float4*)rowsum)[r4];
    s += __logf(v.x) + __logf(v.y) + __logf(v.z) + __logf(v.w);
  }
  for (int i4 = t; i4 < 4096 / 4; i4 += 256) {
    const float4 d = ((const float4*)rowdiag)[i4];
    s -= 2.0f * (d.x + d.y + d.z + d.w);
  }
  #pragma unroll
  for (int off = 32; off > 0; off >>= 1) s += __shfl_xor(s, off, 64);
  __shared__ float wsum[4];
  const int w = t >> 6, lane = t & 63;
  if (lane == 0) wsum[w] = s;
  __syncthreads();
  if (t == 0) out[0] = (wsum[0] + wsum[1] + wsum[2] + wsum[3]) / (float)NROWS;
}

extern "C" void kernel_launch(void* const* d_in, const int* in_sizes, int n_in,
                              void* d_out, int out_size, void* d_ws, size_t ws_size,
                              hipStream_t stream) {
  const float* x = (const float*)d_in[0];
  const float* y = (const float*)d_in[1];
  float* out = (float*)d_out;

  char* ws = (char*)d_ws;
  __hip_bfloat16* zb = (__hip_bfloat16*)ws;                       // 4 MB
  float* rowsum  = (float*)(ws + (size_t)NROWS * DDIM * 2);       // 32 KB
  float* rowdiag = rowsum + NROWS;                                // 16 KB

  normalize_diag_kernel<<<1024, 256, 0, stream>>>(x, y, zb, rowdiag, rowsum);
  gram_lse_kernel<<<512, 512, 0, stream>>>(zb, rowsum);
  finalize_kernel<<<1, 256, 0, stream>>>(rowsum, rowdiag, out);
}